// Round 4
// baseline (330.886 us; speedup 1.0000x reference)
//
#include <hip/hip_runtime.h>
#include <cstdint>
#include <cstddef>

typedef _Float16 f16;
typedef _Float16 f16x8 __attribute__((ext_vector_type(8)));
typedef _Float16 f16x4 __attribute__((ext_vector_type(4)));
typedef __fp16 h16x2 __attribute__((ext_vector_type(2)));
typedef float f32x4 __attribute__((ext_vector_type(4)));
typedef float f32x16 __attribute__((ext_vector_type(16)));

#define DIM 768
#define NHEAD 12
#define HD 64
#define BATCH 4
#define SEQ 2048
#define MROWS (BATCH*SEQ)   // 8192
#define C3 (3*DIM)          // 2304
#define NBH (BATCH*NHEAD)   // 48

__device__ __forceinline__ f32x4 mfma32(f16x8 a, f16x8 b, f32x4 c) {
  return __builtin_amdgcn_mfma_f32_16x16x32_f16(a, b, c, 0, 0, 0);
}
__device__ __forceinline__ f32x16 mfma3232(f16x8 a, f16x8 b, f32x16 c) {
  return __builtin_amdgcn_mfma_f32_32x32x16_f16(a, b, c, 0, 0, 0);
}

// async global->LDS, 16B per lane; LDS dest = wave-uniform base + lane*16
__device__ __forceinline__ void gl2lds16(const void* g, void* l) {
  __builtin_amdgcn_global_load_lds(
      (const __attribute__((address_space(1))) void*)g,
      (__attribute__((address_space(3))) void*)l, 16, 0, 0);
}

// ---------------- fp32 -> fp16 convert (x, qkv_weight, proj_weight) ----------
__global__ __launch_bounds__(256) void k_convert(
    const float* __restrict__ x, const float* __restrict__ wqkv,
    const float* __restrict__ wproj,
    f16* __restrict__ xh, f16* __restrict__ wqh, f16* __restrict__ wph)
{
  const int NX = MROWS*DIM/4, NW = C3*DIM/4;
  int i = blockIdx.x * 256 + threadIdx.x;
  const float4* src; f16* dst; int idx;
  if (i < NX)         { src = (const float4*)x;     dst = xh;  idx = i; }
  else if (i < NX+NW) { src = (const float4*)wqkv;  dst = wqh; idx = i - NX; }
  else                { src = (const float4*)wproj; dst = wph; idx = i - NX - NW; }
  float4 v = src[idx];
  union { f16 h[4]; uint64_t u; } r;
  r.h[0] = (f16)v.x; r.h[1] = (f16)v.y; r.h[2] = (f16)v.z; r.h[3] = (f16)v.w;
  ((uint64_t*)dst)[idx] = r.u;
}

// ---- 128x128 GEMM core (C = A*B^T, both K-contig), BK=32, dbuf, 1 barrier/iter
__device__ __forceinline__ void gemm_tile(
    const f16* __restrict__ A, const f16* __restrict__ B,
    int lda, int ldb, int K, int am0, int bn0,
    f16* smem, f32x4 acc[4][4])
{
  f16* sA0 = smem;         f16* sA1 = smem + 4096;
  f16* sB0 = smem + 8192;  f16* sB1 = smem + 12288;
  const int tid = threadIdx.x, wid = tid >> 6;
  const int lane = tid & 63, lane15 = lane & 15, quad = lane >> 4;
  const int wm = wid >> 1, wn = wid & 1;

  auto stage = [&](int k0, f16* sA, f16* sB) {
    #pragma unroll
    for (int i = 0; i < 2; i++) {
      int j = i*256 + tid;
      int row = j >> 2;
      int sc  = (j & 3) ^ ((row >> 1) & 3);
      gl2lds16(A + (size_t)(am0 + row)*lda + k0 + sc*8, sA + (i*256 + wid*64)*8);
      gl2lds16(B + (size_t)(bn0 + row)*ldb + k0 + sc*8, sB + (i*256 + wid*64)*8);
    }
  };

  const int NK = K >> 5;
  stage(0, sA0, sB0);
  for (int kk = 0; kk < NK; kk++) {
    f16* cA = (kk & 1) ? sA1 : sA0;
    f16* cB = (kk & 1) ? sB1 : sB0;
    __syncthreads();                    // own-vmcnt drain => tile kk staged
    if (kk + 1 < NK)                    // prefetch kk+1, hidden under compute
      stage((kk + 1) << 5, (kk & 1) ? sA0 : sA1, (kk & 1) ? sB0 : sB1);
    f16x8 af[4], bf[4];
    #pragma unroll
    for (int t = 0; t < 4; t++) {
      int ra = wm*64 + t*16 + lane15;
      af[t] = *(const f16x8*)(cA + ra*32 + ((quad ^ ((ra >> 1) & 3)) << 3));
      int rb = wn*64 + t*16 + lane15;
      bf[t] = *(const f16x8*)(cB + rb*32 + ((quad ^ ((rb >> 1) & 3)) << 3));
    }
    #pragma unroll
    for (int mt = 0; mt < 4; mt++)
      #pragma unroll
      for (int nt = 0; nt < 4; nt++)
        acc[mt][nt] = mfma32(af[mt], bf[nt], acc[mt][nt]);
  }
}

// ---------------- QKV GEMM + bias + scale; orientation-per-region ----
__global__ __launch_bounds__(256, 4) void k_qkv(
    const f16* __restrict__ xh, const f16* __restrict__ wqh,
    const float* __restrict__ q_bias, const float* __restrict__ v_bias,
    f16* __restrict__ Qh, f16* __restrict__ Kh, f16* __restrict__ Vt)
{
  __shared__ f16 smem[16384];           // 32 KB gemm dbuf
  f32x4 acc[4][4];
  const f32x4 z4 = {0.f, 0.f, 0.f, 0.f};
  #pragma unroll
  for (int a = 0; a < 4; a++)
    #pragma unroll
    for (int b = 0; b < 4; b++) acc[a][b] = z4;

  const int tid = threadIdx.x, wid = tid >> 6, lane = tid & 63;
  const int lane15 = lane & 15, quad = lane >> 4;
  const int wm = wid >> 1, wn = wid & 1;
  const int cblk = blockIdx.x * 128;    // qkv-channel block [0, 2304)
  const int mblk = blockIdx.y * 128;    // seq-row block    [0, 8192)
  const int bb = mblk >> 11, nbase = mblk & (SEQ - 1);
  const float QS = 0.125f * 1.4426950408889634f;   // scale * log2(e)

  if (cblk < 2*DIM) {
    // ---- Q/K: swapped GEMM: C[c][m] = W[c]·x[m]
    gemm_tile(wqh, xh, DIM, DIM, DIM, cblk, mblk, smem, acc);
    const bool isQ = (cblk < DIM);
    #pragma unroll
    for (int mt = 0; mt < 4; mt++) {
      int c0 = cblk + wm*64 + mt*16 + quad*4;          // 4 contig channels
      int cr = isQ ? c0 : (c0 - DIM);
      int h = cr >> 6, d0 = cr & 63;
      float4 qb4 = isQ ? *(const float4*)(q_bias + c0) : make_float4(0,0,0,0);
      f16* dst = isQ ? Qh : Kh;
      f16* base = dst + (((size_t)(bb*NHEAD + h)*SEQ + nbase) << 6) + d0;
      #pragma unroll
      for (int nt = 0; nt < 4; nt++) {
        int n = wn*64 + nt*16 + lane15;                // seq rel
        f32x4 v = acc[mt][nt];
        f16x4 hv;
        if (isQ) {
          hv[0] = (f16)((v[0] + qb4.x) * QS); hv[1] = (f16)((v[1] + qb4.y) * QS);
          hv[2] = (f16)((v[2] + qb4.z) * QS); hv[3] = (f16)((v[3] + qb4.w) * QS);
        } else {
          hv[0] = (f16)v[0]; hv[1] = (f16)v[1]; hv[2] = (f16)v[2]; hv[3] = (f16)v[3];
        }
        *(f16x4*)(base + ((size_t)n << 6)) = hv;
      }
    }
  } else {
    // ---- V: unswapped GEMM: C[m][c] = x[m]·W[c]
    gemm_tile(xh, wqh, DIM, DIM, DIM, mblk, cblk, smem, acc);
    #pragma unroll
    for (int nt = 0; nt < 4; nt++) {
      int c = cblk + wn*64 + nt*16 + lane15;           // one channel per lane
      int c2 = c - 2*DIM;
      int h = c2 >> 6, d = c2 & 63;
      float b = v_bias[c2];
      f16* base = Vt + ((size_t)(bb*NHEAD + h)*HD + d)*SEQ + nbase;
      #pragma unroll
      for (int mt = 0; mt < 4; mt++) {
        int n0 = wm*64 + mt*16 + quad*4;               // 4 contig seq
        f32x4 v = acc[mt][nt];
        f16x4 hv = {(f16)(v[0]+b), (f16)(v[1]+b), (f16)(v[2]+b), (f16)(v[3]+b)};
        *(f16x4*)(base + n0) = hv;
      }
    }
  }
}

// ---------------- attention: 32x32x16 MFMA, zero cross-lane ops --------------
// Per wave: 32 q rows. S^T(32kv x 32q) = K·Q^T via 4 mfma_32x32x16 (K in LDS,
// XOR-swizzled, DMA dbuf, 1 barrier/tile). P^T = exp2(S^T) feeds PV *in its
// natural C-register order*: MFMA sums over k-slots, so permuting BOTH
// operands' k-layout identically is a no-op. P slot j holds kv
// (j&3)+8*(j>>2)+4*hi, so V A-frags are loaded with the SAME permutation:
// two f16x4 runs at kv p+4hi and p+8+4hi per fragment, straight from Vt
// (L2-resident; prefetched one chunk deep via vA/vB register rotation).
// Row sums via ones-A mfma (k-permutation-insensitive).
#define KVT 128
#define NIT (SEQ/KVT)
__global__ __launch_bounds__(256, 3) void k_attn(
    const f16* __restrict__ Qh, const f16* __restrict__ Kh,
    const f16* __restrict__ Vt, f16* __restrict__ attnh)
{
  __shared__ f16 smem[16384];           // K dbuf 2x16KB; reused by epilogue
  f16* sK0 = smem;
  f16* sK1 = smem + 8192;

  const int tid = threadIdx.x, wid = tid >> 6, lane = tid & 63;
  const int l31 = lane & 31, hi = lane >> 5;

  // XCD-co-locating remap: all 16 q-blocks of a bh land on the same XCD
  const int L = blockIdx.x;
  const int xcd = L & 7, kk = L >> 3;
  const int bh = xcd + 8*(kk >> 4);
  const int q0 = (kk & 15) * 128;
  const int qw = q0 + wid*32;

  const f16* Kbh = Kh + (size_t)bh*SEQ*HD;
  const f16* Vbh = Vt + (size_t)bh*HD*SEQ;

  // Q B-frags for 32x32x16: n=l31 (q), k=hi*8+j (d within 16-slice)
  f16x8 qf[4];
  #pragma unroll
  for (int ks = 0; ks < 4; ks++)
    qf[ks] = *(const f16x8*)(Qh + ((size_t)bh*SEQ + qw + l31)*HD + ks*16 + hi*8);

  const f32x16 z16 = {0.f,0.f,0.f,0.f, 0.f,0.f,0.f,0.f,
                      0.f,0.f,0.f,0.f, 0.f,0.f,0.f,0.f};
  f32x16 o0 = z16, o1 = z16, sacc = z16;
  f16x8 one8;
  #pragma unroll
  for (int j = 0; j < 8; j++) one8[j] = (f16)1.f;

  auto stageK = [&](int kv0, f16* sK) {
    #pragma unroll
    for (int i = 0; i < 4; i++) {
      int j = i*256 + tid;
      int row = j >> 3;
      int sc  = (j & 7) ^ (row & 7);
      gl2lds16(Kbh + (size_t)(kv0 + row)*HD + sc*8, sK + (i*256 + wid*64)*8);
    }
  };

  // hoisted swizzled LDS offsets (halves): row=c*32+l31, chunk=(2ks+hi)^(row&7)
  int koff[4];
  #pragma unroll
  for (int ks = 0; ks < 4; ks++)
    koff[ks] = l31*64 + (((2*ks + hi) ^ (l31 & 7)) << 3);

  // V with k-permutation sigma(hi,j) = (j&3)+8*(j>>2)+4*hi baked into addrs
  const f16* vb0 = Vbh + (size_t)l31*SEQ + 4*hi;        // d rows 0-31
  const f16* vb1 = Vbh + (size_t)(32 + l31)*SEQ + 4*hi; // d rows 32-63

  f16x4 vA[8], vB[8];
  auto loadV = [&](int p, f16x4* vr) {
    vr[0] = *(const f16x4*)(vb0 + p);
    vr[1] = *(const f16x4*)(vb0 + p + 8);
    vr[2] = *(const f16x4*)(vb0 + p + 16);
    vr[3] = *(const f16x4*)(vb0 + p + 24);
    vr[4] = *(const f16x4*)(vb1 + p);
    vr[5] = *(const f16x4*)(vb1 + p + 8);
    vr[6] = *(const f16x4*)(vb1 + p + 16);
    vr[7] = *(const f16x4*)(vb1 + p + 24);
  };

  // one 32-kv chunk: S^T -> exp2 -> pack (natural order) -> rowsum + PV
#define CHUNK(VCUR, VNXT, coff, PRE)                                          \
  do {                                                                        \
    PRE;                                                                      \
    f32x16 s = z16;                                                           \
    _Pragma("unroll")                                                         \
    for (int ks = 0; ks < 4; ks++) {                                          \
      f16x8 ka = *(const f16x8*)(cK + (coff)*2048 + koff[ks]);                \
      s = mfma3232(ka, qf[ks], s);                                            \
    }                                                                         \
    unsigned h[8];                                                            \
    _Pragma("unroll")                                                         \
    for (int r = 0; r < 8; r++) {                                             \
      union { h16x2 p2; unsigned u; } uu;                                     \
      uu.p2 = __builtin_amdgcn_cvt_pkrtz(__builtin_amdgcn_exp2f(s[2*r]),      \
                                         __builtin_amdgcn_exp2f(s[2*r+1]));   \
      h[r] = uu.u;                                                            \
    }                                                                         \
    union { unsigned w[4]; f16x8 v; } b0u, b1u;                               \
    b0u.w[0]=h[0]; b0u.w[1]=h[1]; b0u.w[2]=h[2]; b0u.w[3]=h[3];               \
    b1u.w[0]=h[4]; b1u.w[1]=h[5]; b1u.w[2]=h[6]; b1u.w[3]=h[7];               \
    union { f16x4 q[2]; f16x8 v; } a00, a01, a10, a11;                        \
    a00.q[0]=VCUR[0]; a00.q[1]=VCUR[1];                                       \
    a01.q[0]=VCUR[2]; a01.q[1]=VCUR[3];                                       \
    a10.q[0]=VCUR[4]; a10.q[1]=VCUR[5];                                       \
    a11.q[0]=VCUR[6]; a11.q[1]=VCUR[7];                                       \
    sacc = mfma3232(one8, b0u.v, sacc);                                       \
    sacc = mfma3232(one8, b1u.v, sacc);                                       \
    o0 = mfma3232(a00.v, b0u.v, o0);                                          \
    o0 = mfma3232(a01.v, b1u.v, o0);                                          \
    o1 = mfma3232(a10.v, b0u.v, o1);                                          \
    o1 = mfma3232(a11.v, b1u.v, o1);                                          \
  } while (0)

  loadV(0, vA);
  stageK(0, sK0);

  for (int it = 0; it < NIT; it++) {
    f16* cK = (it & 1) ? sK1 : sK0;
    __syncthreads();                    // own-vmcnt drain => K(it) staged
    if (it + 1 < NIT)                   // prefetch K(it+1) under compute
      stageK((it + 1)*KVT, (it & 1) ? sK0 : sK1);
    const int p0 = it*KVT;
    CHUNK(vA, vB, 0, loadV(p0 + 32, vB));
    CHUNK(vB, vA, 1, loadV(p0 + 64, vA));
    CHUNK(vA, vB, 2, loadV(p0 + 96, vB));
    CHUNK(vB, vA, 3, if (it + 1 < NIT) loadV(p0 + 128, vA));
  }
#undef CHUNK

  const float inv = 1.f / sacc[0];      // full denominator for q=l31

  // epilogue: transpose O^T -> [q][d] via LDS (reuse sK region), store coalesced
  // stride 72 halves = 144B (16B-aligned rows)
  __syncthreads();                      // all waves done reading sK
  f16* tb = smem + wid * (32 * 72);     // 32 rows x 72 halves per wave
  #pragma unroll
  for (int g = 0; g < 4; g++) {
    // o reg r=4g+e -> d = e + 8g + 4hi (+32 for o1): 4 contig halves
    f16x4 h0v = {(f16)(o0[4*g+0]*inv), (f16)(o0[4*g+1]*inv),
                 (f16)(o0[4*g+2]*inv), (f16)(o0[4*g+3]*inv)};
    *(f16x4*)(tb + l31*72 + g*8 + hi*4) = h0v;
    f16x4 h1v = {(f16)(o1[4*g+0]*inv), (f16)(o1[4*g+1]*inv),
                 (f16)(o1[4*g+2]*inv), (f16)(o1[4*g+3]*inv)};
    *(f16x4*)(tb + l31*72 + 32 + g*8 + hi*4) = h1v;
  }
  __syncthreads();
  const int b = bh / NHEAD, hh = bh % NHEAD;
  #pragma unroll
  for (int i = 0; i < 4; i++) {
    int row = i*8 + (lane >> 3);        // 8 rows per pass, 8 lanes per row
    f16x8 rv = *(const f16x8*)(tb + row*72 + (lane & 7)*8);
    *(f16x8*)(attnh + ((size_t)b*SEQ + qw + row)*DIM + hh*HD + (lane & 7)*8) = rv;
  }
}

// ---------------- proj GEMM + bias, fp32 output (swapped: float4 stores) ----
__global__ __launch_bounds__(256, 4) void k_proj(
    const f16* __restrict__ ah, const f16* __restrict__ wph,
    const float* __restrict__ pbias, float* __restrict__ out)
{
  __shared__ f16 smem[16384];           // 32 KB gemm dbuf
  f32x4 acc[4][4];
  const f32x4 z4 = {0.f, 0.f, 0.f, 0.f};
  #pragma unroll
  for (int a = 0; a < 4; a++)
    #pragma unroll
    for (int b = 0; b < 4; b++) acc[a][b] = z4;

  const int cblk = blockIdx.y * 128;    // out-channel block [0, 768)
  const int mblk = blockIdx.x * 128;    // seq-row block     [0, 8192)
  gemm_tile(wph, ah, DIM, DIM, DIM, cblk, mblk, smem, acc);

  const int tid = threadIdx.x, wid = tid >> 6, lane = tid & 63;
  const int lane15 = lane & 15, quad = lane >> 4;
  const int wm = wid >> 1, wn = wid & 1;
  #pragma unroll
  for (int mt = 0; mt < 4; mt++) {
    int c0 = cblk + wm*64 + mt*16 + quad*4;            // 4 contig channels
    float4 b4 = *(const float4*)(pbias + c0);
    #pragma unroll
    for (int nt = 0; nt < 4; nt++) {
      int m = mblk + wn*64 + nt*16 + lane15;           // seq
      f32x4 v = acc[mt][nt];
      float4 r = make_float4(v[0]+b4.x, v[1]+b4.y, v[2]+b4.z, v[3]+b4.w);
      *(float4*)(out + (size_t)m*DIM + c0) = r;
    }
  }
}

extern "C" void kernel_launch(void* const* d_in, const int* in_sizes, int n_in,
                              void* d_out, int out_size, void* d_ws, size_t ws_size,
                              hipStream_t stream) {
  const float* x    = (const float*)d_in[0];
  const float* wqkv = (const float*)d_in[1];
  const float* qb   = (const float*)d_in[2];
  const float* vb   = (const float*)d_in[3];
  const float* wp   = (const float*)d_in[4];
  const float* pb   = (const float*)d_in[5];
  float* out = (float*)d_out;

  f16* p = (f16*)d_ws;
  f16* xh  = p; p += (size_t)MROWS*DIM;
  f16* wqh = p; p += (size_t)C3*DIM;
  f16* wph = p; p += (size_t)DIM*DIM;
  f16* Qh  = p; p += (size_t)NBH*SEQ*HD;
  f16* Kh  = p; p += (size_t)NBH*SEQ*HD;
  f16* Vt  = p; p += (size_t)NBH*SEQ*HD;
  f16* attnh = xh;                      // xh dead after k_qkv -> reuse

  k_convert<<<8448, 256, 0, stream>>>(x, wqkv, wp, xh, wqh, wph);
  k_qkv<<<dim3(C3/128, MROWS/128), 256, 0, stream>>>(xh, wqh, qb, vb, Qh, Kh, Vt);
  k_attn<<<dim3((SEQ/128)*NBH), 256, 0, stream>>>(Qh, Kh, Vt, attnh);
  k_proj<<<dim3(MROWS/128, DIM/128), 256, 0, stream>>>(attnh, wph, pb, out);
}

// Round 5
// 220.104 us; speedup vs baseline: 1.5033x; 1.5033x over previous
//
#include <hip/hip_runtime.h>
#include <cstdint>
#include <cstddef>

typedef _Float16 f16;
typedef _Float16 f16x8 __attribute__((ext_vector_type(8)));
typedef _Float16 f16x4 __attribute__((ext_vector_type(4)));
typedef __fp16 h16x2 __attribute__((ext_vector_type(2)));
typedef float f32x4 __attribute__((ext_vector_type(4)));
typedef float f32x16 __attribute__((ext_vector_type(16)));

#define DIM 768
#define NHEAD 12
#define HD 64
#define BATCH 4
#define SEQ 2048
#define MROWS (BATCH*SEQ)   // 8192
#define C3 (3*DIM)          // 2304
#define NBH (BATCH*NHEAD)   // 48

__device__ __forceinline__ f32x4 mfma32(f16x8 a, f16x8 b, f32x4 c) {
  return __builtin_amdgcn_mfma_f32_16x16x32_f16(a, b, c, 0, 0, 0);
}
__device__ __forceinline__ f32x16 mfma3232(f16x8 a, f16x8 b, f32x16 c) {
  return __builtin_amdgcn_mfma_f32_32x32x16_f16(a, b, c, 0, 0, 0);
}

// async global->LDS, 16B per lane; LDS dest = wave-uniform base + lane*16
__device__ __forceinline__ void gl2lds16(const void* g, void* l) {
  __builtin_amdgcn_global_load_lds(
      (const __attribute__((address_space(1))) void*)g,
      (__attribute__((address_space(3))) void*)l, 16, 0, 0);
}

// ---------------- fp32 -> fp16 convert (x, qkv_weight, proj_weight) ----------
__global__ __launch_bounds__(256) void k_convert(
    const float* __restrict__ x, const float* __restrict__ wqkv,
    const float* __restrict__ wproj,
    f16* __restrict__ xh, f16* __restrict__ wqh, f16* __restrict__ wph)
{
  const int NX = MROWS*DIM/4, NW = C3*DIM/4;
  int i = blockIdx.x * 256 + threadIdx.x;
  const float4* src; f16* dst; int idx;
  if (i < NX)         { src = (const float4*)x;     dst = xh;  idx = i; }
  else if (i < NX+NW) { src = (const float4*)wqkv;  dst = wqh; idx = i - NX; }
  else                { src = (const float4*)wproj; dst = wph; idx = i - NX - NW; }
  float4 v = src[idx];
  union { f16 h[4]; uint64_t u; } r;
  r.h[0] = (f16)v.x; r.h[1] = (f16)v.y; r.h[2] = (f16)v.z; r.h[3] = (f16)v.w;
  ((uint64_t*)dst)[idx] = r.u;
}

// ---- 128x128 GEMM core (C = A*B^T, both K-contig), BK=32, dbuf, 1 barrier/iter
__device__ __forceinline__ void gemm_tile(
    const f16* __restrict__ A, const f16* __restrict__ B,
    int lda, int ldb, int K, int am0, int bn0,
    f16* smem, f32x4 acc[4][4])
{
  f16* sA0 = smem;         f16* sA1 = smem + 4096;
  f16* sB0 = smem + 8192;  f16* sB1 = smem + 12288;
  const int tid = threadIdx.x, wid = tid >> 6;
  const int lane = tid & 63, lane15 = lane & 15, quad = lane >> 4;
  const int wm = wid >> 1, wn = wid & 1;

  auto stage = [&](int k0, f16* sA, f16* sB) {
    #pragma unroll
    for (int i = 0; i < 2; i++) {
      int j = i*256 + tid;
      int row = j >> 2;
      int sc  = (j & 3) ^ ((row >> 1) & 3);
      gl2lds16(A + (size_t)(am0 + row)*lda + k0 + sc*8, sA + (i*256 + wid*64)*8);
      gl2lds16(B + (size_t)(bn0 + row)*ldb + k0 + sc*8, sB + (i*256 + wid*64)*8);
    }
  };

  const int NK = K >> 5;
  stage(0, sA0, sB0);
  for (int kk = 0; kk < NK; kk++) {
    f16* cA = (kk & 1) ? sA1 : sA0;
    f16* cB = (kk & 1) ? sB1 : sB0;
    __syncthreads();                    // own-vmcnt drain => tile kk staged
    if (kk + 1 < NK)                    // prefetch kk+1, hidden under compute
      stage((kk + 1) << 5, (kk & 1) ? sA0 : sA1, (kk & 1) ? sB0 : sB1);
    f16x8 af[4], bf[4];
    #pragma unroll
    for (int t = 0; t < 4; t++) {
      int ra = wm*64 + t*16 + lane15;
      af[t] = *(const f16x8*)(cA + ra*32 + ((quad ^ ((ra >> 1) & 3)) << 3));
      int rb = wn*64 + t*16 + lane15;
      bf[t] = *(const f16x8*)(cB + rb*32 + ((quad ^ ((rb >> 1) & 3)) << 3));
    }
    #pragma unroll
    for (int mt = 0; mt < 4; mt++)
      #pragma unroll
      for (int nt = 0; nt < 4; nt++)
        acc[mt][nt] = mfma32(af[mt], bf[nt], acc[mt][nt]);
  }
}

// ---------------- QKV GEMM + bias + scale; orientation-per-region ----
__global__ __launch_bounds__(256, 4) void k_qkv(
    const f16* __restrict__ xh, const f16* __restrict__ wqh,
    const float* __restrict__ q_bias, const float* __restrict__ v_bias,
    f16* __restrict__ Qh, f16* __restrict__ Kh, f16* __restrict__ Vt)
{
  __shared__ f16 smem[16384];           // 32 KB gemm dbuf
  f32x4 acc[4][4];
  const f32x4 z4 = {0.f, 0.f, 0.f, 0.f};
  #pragma unroll
  for (int a = 0; a < 4; a++)
    #pragma unroll
    for (int b = 0; b < 4; b++) acc[a][b] = z4;

  const int tid = threadIdx.x, wid = tid >> 6, lane = tid & 63;
  const int lane15 = lane & 15, quad = lane >> 4;
  const int wm = wid >> 1, wn = wid & 1;
  const int cblk = blockIdx.x * 128;    // qkv-channel block [0, 2304)
  const int mblk = blockIdx.y * 128;    // seq-row block    [0, 8192)
  const int bb = mblk >> 11, nbase = mblk & (SEQ - 1);
  const float QS = 0.125f * 1.4426950408889634f;   // scale * log2(e)

  if (cblk < 2*DIM) {
    // ---- Q/K: swapped GEMM: C[c][m] = W[c]·x[m]
    gemm_tile(wqh, xh, DIM, DIM, DIM, cblk, mblk, smem, acc);
    const bool isQ = (cblk < DIM);
    #pragma unroll
    for (int mt = 0; mt < 4; mt++) {
      int c0 = cblk + wm*64 + mt*16 + quad*4;          // 4 contig channels
      int cr = isQ ? c0 : (c0 - DIM);
      int h = cr >> 6, d0 = cr & 63;
      float4 qb4 = isQ ? *(const float4*)(q_bias + c0) : make_float4(0,0,0,0);
      f16* dst = isQ ? Qh : Kh;
      f16* base = dst + (((size_t)(bb*NHEAD + h)*SEQ + nbase) << 6) + d0;
      #pragma unroll
      for (int nt = 0; nt < 4; nt++) {
        int n = wn*64 + nt*16 + lane15;                // seq rel
        f32x4 v = acc[mt][nt];
        f16x4 hv;
        if (isQ) {
          hv[0] = (f16)((v[0] + qb4.x) * QS); hv[1] = (f16)((v[1] + qb4.y) * QS);
          hv[2] = (f16)((v[2] + qb4.z) * QS); hv[3] = (f16)((v[3] + qb4.w) * QS);
        } else {
          hv[0] = (f16)v[0]; hv[1] = (f16)v[1]; hv[2] = (f16)v[2]; hv[3] = (f16)v[3];
        }
        *(f16x4*)(base + ((size_t)n << 6)) = hv;
      }
    }
  } else {
    // ---- V: unswapped GEMM: C[m][c] = x[m]·W[c]
    gemm_tile(xh, wqh, DIM, DIM, DIM, mblk, cblk, smem, acc);
    #pragma unroll
    for (int nt = 0; nt < 4; nt++) {
      int c = cblk + wn*64 + nt*16 + lane15;           // one channel per lane
      int c2 = c - 2*DIM;
      int h = c2 >> 6, d = c2 & 63;
      float b = v_bias[c2];
      f16* base = Vt + ((size_t)(bb*NHEAD + h)*HD + d)*SEQ + nbase;
      #pragma unroll
      for (int mt = 0; mt < 4; mt++) {
        int n0 = wm*64 + mt*16 + quad*4;               // 4 contig seq
        f32x4 v = acc[mt][nt];
        f16x4 hv = {(f16)(v[0]+b), (f16)(v[1]+b), (f16)(v[2]+b), (f16)(v[3]+b)};
        *(f16x4*)(base + n0) = hv;
      }
    }
  }
}

// ---------------- attention: 32x32x16 MFMA + fully-LDS operands --------------
// Round-0's proven staging skeleton (DMA-dbuf K, reg-staged V in LDS stride
// 132, 2 barriers/tile) + round-4's verified permutation-free P math:
// MFMA sums over k-slots, so P^T in its natural C-register packing (slot j
// <-> kv (j&3)+8*(j>>2)+4*hi) multiplies V fragments read with the SAME
// permutation: two ds_read_b64 per fragment at kv offsets {4hi..}, {8+4hi..}.
// Zero cross-lane ops, zero global loads in the inner loop.
#define KVT 128
#define NIT (SEQ/KVT)
__global__ __launch_bounds__(256, 3) void k_attn(
    const f16* __restrict__ Qh, const f16* __restrict__ Kh,
    const f16* __restrict__ Vt, f16* __restrict__ attnh)
{
  __shared__ f16 smem[2*8192 + 64*132];  // sK0, sK1 (16KB each), sV 16.5KB
  f16* sK0 = smem;
  f16* sK1 = smem + 8192;
  f16* sV  = smem + 16384;

  const int tid = threadIdx.x, wid = tid >> 6, lane = tid & 63;
  const int l31 = lane & 31, hi = lane >> 5;

  // XCD-co-locating remap: all 16 q-blocks of a bh land on the same XCD
  const int L = blockIdx.x;
  const int xcd = L & 7, kk = L >> 3;
  const int bh = xcd + 8*(kk >> 4);
  const int q0 = (kk & 15) * 128;
  const int qw = q0 + wid*32;

  const f16* Kbh = Kh + (size_t)bh*SEQ*HD;
  const f16* Vbh = Vt + (size_t)bh*HD*SEQ;

  // Q B-frags for 32x32x16: n=l31 (q), k=hi*8+j (d within 16-slice)
  f16x8 qf[4];
  #pragma unroll
  for (int ks = 0; ks < 4; ks++)
    qf[ks] = *(const f16x8*)(Qh + ((size_t)bh*SEQ + qw + l31)*HD + ks*16 + hi*8);

  const f32x16 z16 = {0.f,0.f,0.f,0.f, 0.f,0.f,0.f,0.f,
                      0.f,0.f,0.f,0.f, 0.f,0.f,0.f,0.f};
  f32x16 o0 = z16, o1 = z16, sacc = z16;
  f16x8 one8;
  #pragma unroll
  for (int j = 0; j < 8; j++) one8[j] = (f16)1.f;

  auto stageK = [&](int kv0, f16* sK) {
    #pragma unroll
    for (int i = 0; i < 4; i++) {
      int j = i*256 + tid;
      int row = j >> 3;
      int sc  = (j & 7) ^ (row & 7);
      gl2lds16(Kbh + (size_t)(kv0 + row)*HD + sc*8, sK + (i*256 + wid*64)*8);
    }
  };

  // hoisted swizzled K offsets (halves): row=c*32+l31, chunk=(2ks+hi)^(row&7)
  int koff[4];
  #pragma unroll
  for (int ks = 0; ks < 4; ks++)
    koff[ks] = l31*64 + (((2*ks + hi) ^ (l31 & 7)) << 3);

  // V staging assignment: thread -> (row d, 32-half group)
  const int vrow = tid >> 2, vcg = (tid & 3) * 32;
  const f16* vsrc = Vbh + (size_t)vrow*SEQ + vcg;

  // prologue: DMA K(0), prefetch V(0) into regs
  stageK(0, sK0);
  f16x8 vreg[4];
  #pragma unroll
  for (int j = 0; j < 4; j++) vreg[j] = *(const f16x8*)(vsrc + j*8);

  for (int it = 0; it < NIT; it++) {
    f16* cK = (it & 1) ? sK1 : sK0;
    __syncthreads();                    // drains own DMA(it) + V prefetch
    // write sV (stride 132) from prefetched regs
    #pragma unroll
    for (int j = 0; j < 4; j++) {
      union { f16x8 v; f16x4 h[2]; } u; u.v = vreg[j];
      *(f16x4*)(sV + vrow*132 + vcg + j*8)     = u.h[0];
      *(f16x4*)(sV + vrow*132 + vcg + j*8 + 4) = u.h[1];
    }
    __syncthreads();                    // cheap: only lgkm (ds_writes) pending
    if (it + 1 < NIT) {                 // hidden under compute:
      stageK((it + 1)*KVT, (it & 1) ? sK0 : sK1);
      #pragma unroll
      for (int j = 0; j < 4; j++)
        vreg[j] = *(const f16x8*)(vsrc + (it + 1)*KVT + j*8);
    }

    #pragma unroll
    for (int c = 0; c < 4; c++) {       // kv in chunks of 32
      // V A-frags from sV, permuted k-order baked into addresses:
      // kv = c*32 + g*16 + {4hi..4hi+3, 8+4hi..11+4hi}
      const int vo = c*32 + 4*hi;
      union { f16x4 q[2]; f16x8 v; } a00, a01, a10, a11;
      a00.q[0] = *(const f16x4*)(sV + l31*132 + vo);
      a00.q[1] = *(const f16x4*)(sV + l31*132 + vo + 8);
      a01.q[0] = *(const f16x4*)(sV + l31*132 + vo + 16);
      a01.q[1] = *(const f16x4*)(sV + l31*132 + vo + 24);
      a10.q[0] = *(const f16x4*)(sV + (32 + l31)*132 + vo);
      a10.q[1] = *(const f16x4*)(sV + (32 + l31)*132 + vo + 8);
      a11.q[0] = *(const f16x4*)(sV + (32 + l31)*132 + vo + 16);
      a11.q[1] = *(const f16x4*)(sV + (32 + l31)*132 + vo + 24);

      // S^T = K·Q^T over d=64 (A=K: m=kv=l31, k=hi*8+j)
      f32x16 s = z16;
      #pragma unroll
      for (int ks = 0; ks < 4; ks++) {
        f16x8 ka = *(const f16x8*)(cK + c*2048 + koff[ks]);
        s = mfma3232(ka, qf[ks], s);
      }

      // P^T = exp2(S^T), packed to f16 pairs in natural C order
      unsigned h[8];
      #pragma unroll
      for (int r = 0; r < 8; r++) {
        union { h16x2 p2; unsigned u; } uu;
        uu.p2 = __builtin_amdgcn_cvt_pkrtz(__builtin_amdgcn_exp2f(s[2*r]),
                                           __builtin_amdgcn_exp2f(s[2*r+1]));
        h[r] = uu.u;
      }
      union { unsigned w[4]; f16x8 v; } b0u, b1u;
      b0u.w[0]=h[0]; b0u.w[1]=h[1]; b0u.w[2]=h[2]; b0u.w[3]=h[3];
      b1u.w[0]=h[4]; b1u.w[1]=h[5]; b1u.w[2]=h[6]; b1u.w[3]=h[7];

      // row sums (ones-A, k-permutation-insensitive) + O^T += V^T·P^T
      sacc = mfma3232(one8, b0u.v, sacc);
      sacc = mfma3232(one8, b1u.v, sacc);
      o0 = mfma3232(a00.v, b0u.v, o0);
      o0 = mfma3232(a01.v, b1u.v, o0);
      o1 = mfma3232(a10.v, b0u.v, o1);
      o1 = mfma3232(a11.v, b1u.v, o1);
    }
  }

  const float inv = 1.f / sacc[0];      // full denominator for q=l31

  // epilogue: transpose O^T -> [q][d] via LDS (reuse sK region), store coalesced
  // stride 72 halves = 144B (16B-aligned rows)
  __syncthreads();                      // all waves done reading sK/sV
  f16* tb = smem + wid * (32 * 72);     // 32 rows x 72 halves per wave
  #pragma unroll
  for (int g = 0; g < 4; g++) {
    // o reg r=4g+e -> d = e + 8g + 4hi (+32 for o1): 4 contig halves
    f16x4 h0v = {(f16)(o0[4*g+0]*inv), (f16)(o0[4*g+1]*inv),
                 (f16)(o0[4*g+2]*inv), (f16)(o0[4*g+3]*inv)};
    *(f16x4*)(tb + l31*72 + g*8 + hi*4) = h0v;
    f16x4 h1v = {(f16)(o1[4*g+0]*inv), (f16)(o1[4*g+1]*inv),
                 (f16)(o1[4*g+2]*inv), (f16)(o1[4*g+3]*inv)};
    *(f16x4*)(tb + l31*72 + 32 + g*8 + hi*4) = h1v;
  }
  __syncthreads();
  const int b = bh / NHEAD, hh = bh % NHEAD;
  #pragma unroll
  for (int i = 0; i < 4; i++) {
    int row = i*8 + (lane >> 3);        // 8 rows per pass, 8 lanes per row
    f16x8 rv = *(const f16x8*)(tb + row*72 + (lane & 7)*8);
    *(f16x8*)(attnh + ((size_t)b*SEQ + qw + row)*DIM + hh*HD + (lane & 7)*8) = rv;
  }
}

// ---------------- proj GEMM + bias, fp32 output (swapped: float4 stores) ----
__global__ __launch_bounds__(256, 4) void k_proj(
    const f16* __restrict__ ah, const f16* __restrict__ wph,
    const float* __restrict__ pbias, float* __restrict__ out)
{
  __shared__ f16 smem[16384];           // 32 KB gemm dbuf
  f32x4 acc[4][4];
  const f32x4 z4 = {0.f, 0.f, 0.f, 0.f};
  #pragma unroll
  for (int a = 0; a < 4; a++)
    #pragma unroll
    for (int b = 0; b < 4; b++) acc[a][b] = z4;

  const int cblk = blockIdx.y * 128;    // out-channel block [0, 768)
  const int mblk = blockIdx.x * 128;    // seq-row block     [0, 8192)
  gemm_tile(wph, ah, DIM, DIM, DIM, cblk, mblk, smem, acc);

  const int tid = threadIdx.x, wid = tid >> 6, lane = tid & 63;
  const int lane15 = lane & 15, quad = lane >> 4;
  const int wm = wid >> 1, wn = wid & 1;
  #pragma unroll
  for (int mt = 0; mt < 4; mt++) {
    int c0 = cblk + wm*64 + mt*16 + quad*4;            // 4 contig channels
    float4 b4 = *(const float4*)(pbias + c0);
    #pragma unroll
    for (int nt = 0; nt < 4; nt++) {
      int m = mblk + wn*64 + nt*16 + lane15;           // seq
      f32x4 v = acc[mt][nt];
      float4 r = make_float4(v[0]+b4.x, v[1]+b4.y, v[2]+b4.z, v[3]+b4.w);
      *(float4*)(out + (size_t)m*DIM + c0) = r;
    }
  }
}

extern "C" void kernel_launch(void* const* d_in, const int* in_sizes, int n_in,
                              void* d_out, int out_size, void* d_ws, size_t ws_size,
                              hipStream_t stream) {
  const float* x    = (const float*)d_in[0];
  const float* wqkv = (const float*)d_in[1];
  const float* qb   = (const float*)d_in[2];
  const float* vb   = (const float*)d_in[3];
  const float* wp   = (const float*)d_in[4];
  const float* pb   = (const float*)d_in[5];
  float* out = (float*)d_out;

  f16* p = (f16*)d_ws;
  f16* xh  = p; p += (size_t)MROWS*DIM;
  f16* wqh = p; p += (size_t)C3*DIM;
  f16* wph = p; p += (size_t)DIM*DIM;
  f16* Qh  = p; p += (size_t)NBH*SEQ*HD;
  f16* Kh  = p; p += (size_t)NBH*SEQ*HD;
  f16* Vt  = p; p += (size_t)NBH*SEQ*HD;
  f16* attnh = xh;                      // xh dead after k_qkv -> reuse

  k_convert<<<8448, 256, 0, stream>>>(x, wqkv, wp, xh, wqh, wph);
  k_qkv<<<dim3(C3/128, MROWS/128), 256, 0, stream>>>(xh, wqh, qb, vb, Qh, Kh, Vt);
  k_attn<<<dim3((SEQ/128)*NBH), 256, 0, stream>>>(Qh, Kh, Vt, attnh);
  k_proj<<<dim3(MROWS/128, DIM/128), 256, 0, stream>>>(attnh, wph, pb, out);
}

// Round 6
// 219.413 us; speedup vs baseline: 1.5081x; 1.0032x over previous
//
#include <hip/hip_runtime.h>
#include <cstdint>
#include <cstddef>

typedef _Float16 f16;
typedef _Float16 f16x8 __attribute__((ext_vector_type(8)));
typedef _Float16 f16x4 __attribute__((ext_vector_type(4)));
typedef __fp16 h16x2 __attribute__((ext_vector_type(2)));
typedef float f32x4 __attribute__((ext_vector_type(4)));
typedef float f32x16 __attribute__((ext_vector_type(16)));

#define DIM 768
#define NHEAD 12
#define HD 64
#define BATCH 4
#define SEQ 2048
#define MROWS (BATCH*SEQ)   // 8192
#define C3 (3*DIM)          // 2304
#define NBH (BATCH*NHEAD)   // 48

__device__ __forceinline__ f32x4 mfma32(f16x8 a, f16x8 b, f32x4 c) {
  return __builtin_amdgcn_mfma_f32_16x16x32_f16(a, b, c, 0, 0, 0);
}
__device__ __forceinline__ f32x16 mfma3232(f16x8 a, f16x8 b, f32x16 c) {
  return __builtin_amdgcn_mfma_f32_32x32x16_f16(a, b, c, 0, 0, 0);
}

// async global->LDS, 16B per lane; LDS dest = wave-uniform base + lane*16
__device__ __forceinline__ void gl2lds16(const void* g, void* l) {
  __builtin_amdgcn_global_load_lds(
      (const __attribute__((address_space(1))) void*)g,
      (__attribute__((address_space(3))) void*)l, 16, 0, 0);
}

// ---------------- fp32 -> fp16 convert (x, qkv_weight, proj_weight) ----------
__global__ __launch_bounds__(256) void k_convert(
    const float* __restrict__ x, const float* __restrict__ wqkv,
    const float* __restrict__ wproj,
    f16* __restrict__ xh, f16* __restrict__ wqh, f16* __restrict__ wph)
{
  const int NX = MROWS*DIM/4, NW = C3*DIM/4;
  int i = blockIdx.x * 256 + threadIdx.x;
  const float4* src; f16* dst; int idx;
  if (i < NX)         { src = (const float4*)x;     dst = xh;  idx = i; }
  else if (i < NX+NW) { src = (const float4*)wqkv;  dst = wqh; idx = i - NX; }
  else                { src = (const float4*)wproj; dst = wph; idx = i - NX - NW; }
  float4 v = src[idx];
  union { f16 h[4]; uint64_t u; } r;
  r.h[0] = (f16)v.x; r.h[1] = (f16)v.y; r.h[2] = (f16)v.z; r.h[3] = (f16)v.w;
  ((uint64_t*)dst)[idx] = r.u;
}

// ---- 128x128 GEMM core (C = A*B^T, both K-contig), BK=32, dbuf, 1 barrier/iter
__device__ __forceinline__ void gemm_tile(
    const f16* __restrict__ A, const f16* __restrict__ B,
    int lda, int ldb, int K, int am0, int bn0,
    f16* smem, f32x4 acc[4][4])
{
  f16* sA0 = smem;         f16* sA1 = smem + 4096;
  f16* sB0 = smem + 8192;  f16* sB1 = smem + 12288;
  const int tid = threadIdx.x, wid = tid >> 6;
  const int lane = tid & 63, lane15 = lane & 15, quad = lane >> 4;
  const int wm = wid >> 1, wn = wid & 1;

  auto stage = [&](int k0, f16* sA, f16* sB) {
    #pragma unroll
    for (int i = 0; i < 2; i++) {
      int j = i*256 + tid;
      int row = j >> 2;
      int sc  = (j & 3) ^ ((row >> 1) & 3);
      gl2lds16(A + (size_t)(am0 + row)*lda + k0 + sc*8, sA + (i*256 + wid*64)*8);
      gl2lds16(B + (size_t)(bn0 + row)*ldb + k0 + sc*8, sB + (i*256 + wid*64)*8);
    }
  };

  const int NK = K >> 5;
  stage(0, sA0, sB0);
  for (int kk = 0; kk < NK; kk++) {
    f16* cA = (kk & 1) ? sA1 : sA0;
    f16* cB = (kk & 1) ? sB1 : sB0;
    __syncthreads();                    // own-vmcnt drain => tile kk staged
    if (kk + 1 < NK)                    // prefetch kk+1, hidden under compute
      stage((kk + 1) << 5, (kk & 1) ? sA0 : sA1, (kk & 1) ? sB0 : sB1);
    f16x8 af[4], bf[4];
    #pragma unroll
    for (int t = 0; t < 4; t++) {
      int ra = wm*64 + t*16 + lane15;
      af[t] = *(const f16x8*)(cA + ra*32 + ((quad ^ ((ra >> 1) & 3)) << 3));
      int rb = wn*64 + t*16 + lane15;
      bf[t] = *(const f16x8*)(cB + rb*32 + ((quad ^ ((rb >> 1) & 3)) << 3));
    }
    #pragma unroll
    for (int mt = 0; mt < 4; mt++)
      #pragma unroll
      for (int nt = 0; nt < 4; nt++)
        acc[mt][nt] = mfma32(af[mt], bf[nt], acc[mt][nt]);
  }
}

// ---------------- QKV GEMM + bias + scale; orientation-per-region ----
__global__ __launch_bounds__(256, 4) void k_qkv(
    const f16* __restrict__ xh, const f16* __restrict__ wqh,
    const float* __restrict__ q_bias, const float* __restrict__ v_bias,
    f16* __restrict__ Qh, f16* __restrict__ Kh, f16* __restrict__ Vt)
{
  __shared__ f16 smem[16384];           // 32 KB gemm dbuf
  f32x4 acc[4][4];
  const f32x4 z4 = {0.f, 0.f, 0.f, 0.f};
  #pragma unroll
  for (int a = 0; a < 4; a++)
    #pragma unroll
    for (int b = 0; b < 4; b++) acc[a][b] = z4;

  const int tid = threadIdx.x, wid = tid >> 6, lane = tid & 63;
  const int lane15 = lane & 15, quad = lane >> 4;
  const int wm = wid >> 1, wn = wid & 1;
  const int cblk = blockIdx.x * 128;    // qkv-channel block [0, 2304)
  const int mblk = blockIdx.y * 128;    // seq-row block    [0, 8192)
  const int bb = mblk >> 11, nbase = mblk & (SEQ - 1);
  const float QS = 0.125f * 1.4426950408889634f;   // scale * log2(e)

  if (cblk < 2*DIM) {
    // ---- Q/K: swapped GEMM: C[c][m] = W[c]·x[m]
    gemm_tile(wqh, xh, DIM, DIM, DIM, cblk, mblk, smem, acc);
    const bool isQ = (cblk < DIM);
    #pragma unroll
    for (int mt = 0; mt < 4; mt++) {
      int c0 = cblk + wm*64 + mt*16 + quad*4;          // 4 contig channels
      int cr = isQ ? c0 : (c0 - DIM);
      int h = cr >> 6, d0 = cr & 63;
      float4 qb4 = isQ ? *(const float4*)(q_bias + c0) : make_float4(0,0,0,0);
      f16* dst = isQ ? Qh : Kh;
      f16* base = dst + (((size_t)(bb*NHEAD + h)*SEQ + nbase) << 6) + d0;
      #pragma unroll
      for (int nt = 0; nt < 4; nt++) {
        int n = wn*64 + nt*16 + lane15;                // seq rel
        f32x4 v = acc[mt][nt];
        f16x4 hv;
        if (isQ) {
          hv[0] = (f16)((v[0] + qb4.x) * QS); hv[1] = (f16)((v[1] + qb4.y) * QS);
          hv[2] = (f16)((v[2] + qb4.z) * QS); hv[3] = (f16)((v[3] + qb4.w) * QS);
        } else {
          hv[0] = (f16)v[0]; hv[1] = (f16)v[1]; hv[2] = (f16)v[2]; hv[3] = (f16)v[3];
        }
        *(f16x4*)(base + ((size_t)n << 6)) = hv;
      }
    }
  } else {
    // ---- V: unswapped GEMM: C[m][c] = x[m]·W[c]
    gemm_tile(xh, wqh, DIM, DIM, DIM, mblk, cblk, smem, acc);
    #pragma unroll
    for (int nt = 0; nt < 4; nt++) {
      int c = cblk + wn*64 + nt*16 + lane15;           // one channel per lane
      int c2 = c - 2*DIM;
      int h = c2 >> 6, d = c2 & 63;
      float b = v_bias[c2];
      f16* base = Vt + ((size_t)(bb*NHEAD + h)*HD + d)*SEQ + nbase;
      #pragma unroll
      for (int mt = 0; mt < 4; mt++) {
        int n0 = wm*64 + mt*16 + quad*4;               // 4 contig seq
        f32x4 v = acc[mt][nt];
        f16x4 hv = {(f16)(v[0]+b), (f16)(v[1]+b), (f16)(v[2]+b), (f16)(v[3]+b)};
        *(f16x4*)(base + n0) = hv;
      }
    }
  }
}

// ---------------- attention: 32x32x16, S-pipelined one chunk ahead ----------
// R5 structure (DMA-dbuf K, reg-staged sV stride 132, permutation-free P:
// slot j <-> kv (j&3)+8*(j>>2)+4*hi on BOTH P and V operands) + this round:
// rotating s0/s1 accumulators so chunk c+1's 4 S-MFMAs (and their K ds_reads)
// are in flight while chunk c's exp/pack/PV runs; s_setprio(1) around MFMA
// clusters (T5). Cuts the serial ds_read->S->exp->PV chain stall (~60% of
// k_attn wall at 3 waves/SIMD).
#define KVT 128
#define NIT (SEQ/KVT)
__global__ __launch_bounds__(256, 3) void k_attn(
    const f16* __restrict__ Qh, const f16* __restrict__ Kh,
    const f16* __restrict__ Vt, f16* __restrict__ attnh)
{
  __shared__ f16 smem[2*8192 + 64*132];  // sK0, sK1 (16KB each), sV 16.5KB
  f16* sK0 = smem;
  f16* sK1 = smem + 8192;
  f16* sV  = smem + 16384;

  const int tid = threadIdx.x, wid = tid >> 6, lane = tid & 63;
  const int l31 = lane & 31, hi = lane >> 5;

  // XCD-co-locating remap: all 16 q-blocks of a bh land on the same XCD
  const int L = blockIdx.x;
  const int xcd = L & 7, kk = L >> 3;
  const int bh = xcd + 8*(kk >> 4);
  const int q0 = (kk & 15) * 128;
  const int qw = q0 + wid*32;

  const f16* Kbh = Kh + (size_t)bh*SEQ*HD;
  const f16* Vbh = Vt + (size_t)bh*HD*SEQ;

  // Q B-frags for 32x32x16: n=l31 (q), k=hi*8+j (d within 16-slice)
  f16x8 qf[4];
  #pragma unroll
  for (int ks = 0; ks < 4; ks++)
    qf[ks] = *(const f16x8*)(Qh + ((size_t)bh*SEQ + qw + l31)*HD + ks*16 + hi*8);

  const f32x16 z16 = {0.f,0.f,0.f,0.f, 0.f,0.f,0.f,0.f,
                      0.f,0.f,0.f,0.f, 0.f,0.f,0.f,0.f};
  f32x16 o0 = z16, o1 = z16, sacc = z16;
  f16x8 one8;
  #pragma unroll
  for (int j = 0; j < 8; j++) one8[j] = (f16)1.f;

  auto stageK = [&](int kv0, f16* sK) {
    #pragma unroll
    for (int i = 0; i < 4; i++) {
      int j = i*256 + tid;
      int row = j >> 3;
      int sc  = (j & 7) ^ (row & 7);
      gl2lds16(Kbh + (size_t)(kv0 + row)*HD + sc*8, sK + (i*256 + wid*64)*8);
    }
  };

  // hoisted swizzled K offsets (halves): row=c*32+l31, chunk=(2ks+hi)^(row&7)
  int koff[4];
  #pragma unroll
  for (int ks = 0; ks < 4; ks++)
    koff[ks] = l31*64 + (((2*ks + hi) ^ (l31 & 7)) << 3);

  // V staging assignment: thread -> (row d, 32-half group)
  const int vrow = tid >> 2, vcg = (tid & 3) * 32;
  const f16* vsrc = Vbh + (size_t)vrow*SEQ + vcg;

  // prologue: DMA K(0), prefetch V(0) into regs
  stageK(0, sK0);
  f16x8 vreg[4];
  #pragma unroll
  for (int j = 0; j < 4; j++) vreg[j] = *(const f16x8*)(vsrc + j*8);

  // one pipelined step: V-frags(CC) -> exp/pack(SCUR) -> S(CC+1)->SNXT -> PV(CC)
#define ASTEP(SCUR, SNXT, CC, HASNXT)                                         \
  do {                                                                        \
    const int vo = (CC)*32 + 4*hi;                                            \
    union { f16x4 q[2]; f16x8 v; } a00, a01, a10, a11;                        \
    a00.q[0] = *(const f16x4*)(sV + l31*132 + vo);                            \
    a00.q[1] = *(const f16x4*)(sV + l31*132 + vo + 8);                        \
    a01.q[0] = *(const f16x4*)(sV + l31*132 + vo + 16);                       \
    a01.q[1] = *(const f16x4*)(sV + l31*132 + vo + 24);                       \
    a10.q[0] = *(const f16x4*)(sV + (32 + l31)*132 + vo);                     \
    a10.q[1] = *(const f16x4*)(sV + (32 + l31)*132 + vo + 8);                 \
    a11.q[0] = *(const f16x4*)(sV + (32 + l31)*132 + vo + 16);                \
    a11.q[1] = *(const f16x4*)(sV + (32 + l31)*132 + vo + 24);                \
    unsigned hx[8];                                                           \
    _Pragma("unroll")                                                         \
    for (int r = 0; r < 8; r++) {                                             \
      union { h16x2 p2; unsigned u; } uu;                                     \
      uu.p2 = __builtin_amdgcn_cvt_pkrtz(                                     \
          __builtin_amdgcn_exp2f((SCUR)[2*r]),                                \
          __builtin_amdgcn_exp2f((SCUR)[2*r+1]));                             \
      hx[r] = uu.u;                                                           \
    }                                                                         \
    union { unsigned w[4]; f16x8 v; } b0u, b1u;                               \
    b0u.w[0]=hx[0]; b0u.w[1]=hx[1]; b0u.w[2]=hx[2]; b0u.w[3]=hx[3];           \
    b1u.w[0]=hx[4]; b1u.w[1]=hx[5]; b1u.w[2]=hx[6]; b1u.w[3]=hx[7];           \
    if (HASNXT) {                                                             \
      (SNXT) = z16;                                                           \
      __builtin_amdgcn_s_setprio(1);                                          \
      _Pragma("unroll")                                                       \
      for (int ks = 0; ks < 4; ks++) {                                        \
        f16x8 ka = *(const f16x8*)(cK + ((CC)+1)*2048 + koff[ks]);            \
        (SNXT) = mfma3232(ka, qf[ks], (SNXT));                                \
      }                                                                       \
      __builtin_amdgcn_s_setprio(0);                                          \
    }                                                                         \
    __builtin_amdgcn_s_setprio(1);                                            \
    sacc = mfma3232(one8, b0u.v, sacc);                                       \
    o0 = mfma3232(a00.v, b0u.v, o0);                                          \
    o1 = mfma3232(a10.v, b0u.v, o1);                                          \
    sacc = mfma3232(one8, b1u.v, sacc);                                       \
    o0 = mfma3232(a01.v, b1u.v, o0);                                          \
    o1 = mfma3232(a11.v, b1u.v, o1);                                          \
    __builtin_amdgcn_s_setprio(0);                                            \
  } while (0)

  for (int it = 0; it < NIT; it++) {
    f16* cK = (it & 1) ? sK1 : sK0;
    __syncthreads();                    // drains own DMA(it) + V prefetch
    // write sV (stride 132) from prefetched regs
    #pragma unroll
    for (int j = 0; j < 4; j++) {
      union { f16x8 v; f16x4 h[2]; } u; u.v = vreg[j];
      *(f16x4*)(sV + vrow*132 + vcg + j*8)     = u.h[0];
      *(f16x4*)(sV + vrow*132 + vcg + j*8 + 4) = u.h[1];
    }
    __syncthreads();                    // cheap: only lgkm (ds_writes) pending
    if (it + 1 < NIT) {                 // hidden under compute:
      stageK((it + 1)*KVT, (it & 1) ? sK0 : sK1);
      #pragma unroll
      for (int j = 0; j < 4; j++)
        vreg[j] = *(const f16x8*)(vsrc + (it + 1)*KVT + j*8);
    }

    // S(0) into s0, then pipelined steps with rotating s0/s1
    f32x16 s0, s1;
    s0 = z16;
    __builtin_amdgcn_s_setprio(1);
    #pragma unroll
    for (int ks = 0; ks < 4; ks++) {
      f16x8 ka = *(const f16x8*)(cK + koff[ks]);
      s0 = mfma3232(ka, qf[ks], s0);
    }
    __builtin_amdgcn_s_setprio(0);
    ASTEP(s0, s1, 0, 1);
    ASTEP(s1, s0, 1, 1);
    ASTEP(s0, s1, 2, 1);
    ASTEP(s1, s0, 3, 0);
  }
#undef ASTEP

  const float inv = 1.f / sacc[0];      // full denominator for q=l31

  // epilogue: transpose O^T -> [q][d] via LDS (reuse sK region), store coalesced
  // stride 72 halves = 144B (16B-aligned rows)
  __syncthreads();                      // all waves done reading sK/sV
  f16* tb = smem + wid * (32 * 72);     // 32 rows x 72 halves per wave
  #pragma unroll
  for (int g = 0; g < 4; g++) {
    // o reg r=4g+e -> d = e + 8g + 4hi (+32 for o1): 4 contig halves
    f16x4 h0v = {(f16)(o0[4*g+0]*inv), (f16)(o0[4*g+1]*inv),
                 (f16)(o0[4*g+2]*inv), (f16)(o0[4*g+3]*inv)};
    *(f16x4*)(tb + l31*72 + g*8 + hi*4) = h0v;
    f16x4 h1v = {(f16)(o1[4*g+0]*inv), (f16)(o1[4*g+1]*inv),
                 (f16)(o1[4*g+2]*inv), (f16)(o1[4*g+3]*inv)};
    *(f16x4*)(tb + l31*72 + 32 + g*8 + hi*4) = h1v;
  }
  __syncthreads();
  const int b = bh / NHEAD, hh = bh % NHEAD;
  #pragma unroll
  for (int i = 0; i < 4; i++) {
    int row = i*8 + (lane >> 3);        // 8 rows per pass, 8 lanes per row
    f16x8 rv = *(const f16x8*)(tb + row*72 + (lane & 7)*8);
    *(f16x8*)(attnh + ((size_t)b*SEQ + qw + row)*DIM + hh*HD + (lane & 7)*8) = rv;
  }
}

// ---------------- proj GEMM + bias, fp32 output (swapped: float4 stores) ----
__global__ __launch_bounds__(256, 4) void k_proj(
    const f16* __restrict__ ah, const f16* __restrict__ wph,
    const float* __restrict__ pbias, float* __restrict__ out)
{
  __shared__ f16 smem[16384];           // 32 KB gemm dbuf
  f32x4 acc[4][4];
  const f32x4 z4 = {0.f, 0.f, 0.f, 0.f};
  #pragma unroll
  for (int a = 0; a < 4; a++)
    #pragma unroll
    for (int b = 0; b < 4; b++) acc[a][b] = z4;

  const int cblk = blockIdx.y * 128;    // out-channel block [0, 768)
  const int mblk = blockIdx.x * 128;    // seq-row block     [0, 8192)
  gemm_tile(wph, ah, DIM, DIM, DIM, cblk, mblk, smem, acc);

  const int tid = threadIdx.x, wid = tid >> 6, lane = tid & 63;
  const int lane15 = lane & 15, quad = lane >> 4;
  const int wm = wid >> 1, wn = wid & 1;
  #pragma unroll
  for (int mt = 0; mt < 4; mt++) {
    int c0 = cblk + wm*64 + mt*16 + quad*4;            // 4 contig channels
    float4 b4 = *(const float4*)(pbias + c0);
    #pragma unroll
    for (int nt = 0; nt < 4; nt++) {
      int m = mblk + wn*64 + nt*16 + lane15;           // seq
      f32x4 v = acc[mt][nt];
      float4 r = make_float4(v[0]+b4.x, v[1]+b4.y, v[2]+b4.z, v[3]+b4.w);
      *(float4*)(out + (size_t)m*DIM + c0) = r;
    }
  }
}

extern "C" void kernel_launch(void* const* d_in, const int* in_sizes, int n_in,
                              void* d_out, int out_size, void* d_ws, size_t ws_size,
                              hipStream_t stream) {
  const float* x    = (const float*)d_in[0];
  const float* wqkv = (const float*)d_in[1];
  const float* qb   = (const float*)d_in[2];
  const float* vb   = (const float*)d_in[3];
  const float* wp   = (const float*)d_in[4];
  const float* pb   = (const float*)d_in[5];
  float* out = (float*)d_out;

  f16* p = (f16*)d_ws;
  f16* xh  = p; p += (size_t)MROWS*DIM;
  f16* wqh = p; p += (size_t)C3*DIM;
  f16* wph = p; p += (size_t)DIM*DIM;
  f16* Qh  = p; p += (size_t)NBH*SEQ*HD;
  f16* Kh  = p; p += (size_t)NBH*SEQ*HD;
  f16* Vt  = p; p += (size_t)NBH*SEQ*HD;
  f16* attnh = xh;                      // xh dead after k_qkv -> reuse

  k_convert<<<8448, 256, 0, stream>>>(x, wqkv, wp, xh, wqh, wph);
  k_qkv<<<dim3(C3/128, MROWS/128), 256, 0, stream>>>(xh, wqh, qb, vb, Qh, Kh, Vt);
  k_attn<<<dim3((SEQ/128)*NBH), 256, 0, stream>>>(Qh, Kh, Vt, attnh);
  k_proj<<<dim3(MROWS/128, DIM/128), 256, 0, stream>>>(attnh, wph, pb, out);
}